// Round 2
// baseline (1726.941 us; speedup 1.0000x reference)
//
#include <hip/hip_runtime.h>
#include <hip/hip_bf16.h>
#include <math.h>

#define TT 512   // T
#define BB 128   // B
#define EE 100   // embed dim
#define HH 128   // hidden
#define G4 512   // 4*H
#define K1 256   // 2*H

// ---- layer-0 gx GEMM with fused embedding gather --------------------------
// C[m', n] = sum_k emb[tok(m'), k] * W[n, k] + bih[n] + bhh[n]
// m' = chunk-local row = s*B + b; global t = t_base + t_step*s; tok = x[b*T+t].
// 64x64 tile, 256 threads, 4x4 micro-tile, BK=16, K padded to 112.
__global__ __launch_bounds__(256) void gemm_l0(
    const int* __restrict__ x, const float* __restrict__ emb,
    const float* __restrict__ W,          // (512,100)
    const float* __restrict__ bih, const float* __restrict__ bhh,
    float* __restrict__ C,                // (TC*B, 512) chunk-local
    int t_base, int t_step)
{
    __shared__ float As[16][64];
    __shared__ float Bs[16][64];
    int tid = threadIdx.x;
    int tx = tid & 15, ty = tid >> 4;
    int mBase = blockIdx.x * 64;
    int nBase = blockIdx.y * 64;
    float acc[4][4] = {};
    int row = tid >> 2;      // 0..63
    int kq  = tid & 3;       // 0..3
    // token for this thread's A row
    int mrow = mBase + row;
    int s = mrow >> 7;
    int b = mrow & 127;
    int t = t_base + t_step * s;
    int tok = x[b * TT + t];
    const float* arow = emb + (size_t)tok * EE;
    int wrow = nBase + row;
    const float* wp = W + (size_t)wrow * EE;

    for (int kt = 0; kt < 7; ++kt) {        // 112/16
        int kk = kt * 16 + 4 * kq;
        float4 av, wv;
        av.x = (kk + 0 < EE) ? arow[kk + 0] : 0.f;
        av.y = (kk + 1 < EE) ? arow[kk + 1] : 0.f;
        av.z = (kk + 2 < EE) ? arow[kk + 2] : 0.f;
        av.w = (kk + 3 < EE) ? arow[kk + 3] : 0.f;
        wv.x = (kk + 0 < EE) ? wp[kk + 0] : 0.f;
        wv.y = (kk + 1 < EE) ? wp[kk + 1] : 0.f;
        wv.z = (kk + 2 < EE) ? wp[kk + 2] : 0.f;
        wv.w = (kk + 3 < EE) ? wp[kk + 3] : 0.f;
        __syncthreads();
        As[4*kq+0][row] = av.x; As[4*kq+1][row] = av.y;
        As[4*kq+2][row] = av.z; As[4*kq+3][row] = av.w;
        Bs[4*kq+0][row] = wv.x; Bs[4*kq+1][row] = wv.y;
        Bs[4*kq+2][row] = wv.z; Bs[4*kq+3][row] = wv.w;
        __syncthreads();
        #pragma unroll
        for (int k = 0; k < 16; ++k) {
            float a0 = As[k][ty*4+0], a1 = As[k][ty*4+1];
            float a2 = As[k][ty*4+2], a3 = As[k][ty*4+3];
            float b0 = Bs[k][tx*4+0], b1 = Bs[k][tx*4+1];
            float b2 = Bs[k][tx*4+2], b3 = Bs[k][tx*4+3];
            acc[0][0] += a0*b0; acc[0][1] += a0*b1; acc[0][2] += a0*b2; acc[0][3] += a0*b3;
            acc[1][0] += a1*b0; acc[1][1] += a1*b1; acc[1][2] += a1*b2; acc[1][3] += a1*b3;
            acc[2][0] += a2*b0; acc[2][1] += a2*b1; acc[2][2] += a2*b2; acc[2][3] += a2*b3;
            acc[3][0] += a3*b0; acc[3][1] += a3*b1; acc[3][2] += a3*b2; acc[3][3] += a3*b3;
        }
    }
    #pragma unroll
    for (int i = 0; i < 4; ++i) {
        int m = mBase + ty*4 + i;
        #pragma unroll
        for (int j = 0; j < 4; ++j) {
            int n = nBase + tx*4 + j;
            C[(size_t)m * G4 + n] = acc[i][j] + bih[n] + bhh[n];
        }
    }
}

// ---- layer-1 gx GEMM: A = x1 (T*B, 256) ----------------------------------
__global__ __launch_bounds__(256) void gemm_l1(
    const float* __restrict__ x1,         // (T*B, 256)
    const float* __restrict__ W,          // (512,256)
    const float* __restrict__ bih, const float* __restrict__ bhh,
    float* __restrict__ C,                // (TC*B, 512) chunk-local
    int t_base, int t_step)
{
    __shared__ float As[16][64];
    __shared__ float Bs[16][64];
    int tid = threadIdx.x;
    int tx = tid & 15, ty = tid >> 4;
    int mBase = blockIdx.x * 64;
    int nBase = blockIdx.y * 64;
    float acc[4][4] = {};
    int row = tid >> 2;
    int kq  = tid & 3;
    int mrow = mBase + row;
    int s = mrow >> 7;
    int b = mrow & 127;
    int t = t_base + t_step * s;
    const float* arow = x1 + ((size_t)t * BB + b) * K1;
    const float* wp   = W  + (size_t)(nBase + row) * K1;

    for (int kt = 0; kt < 16; ++kt) {       // 256/16
        int kk = kt * 16 + 4 * kq;
        float4 av = *reinterpret_cast<const float4*>(arow + kk);
        float4 wv = *reinterpret_cast<const float4*>(wp + kk);
        __syncthreads();
        As[4*kq+0][row] = av.x; As[4*kq+1][row] = av.y;
        As[4*kq+2][row] = av.z; As[4*kq+3][row] = av.w;
        Bs[4*kq+0][row] = wv.x; Bs[4*kq+1][row] = wv.y;
        Bs[4*kq+2][row] = wv.z; Bs[4*kq+3][row] = wv.w;
        __syncthreads();
        #pragma unroll
        for (int k = 0; k < 16; ++k) {
            float a0 = As[k][ty*4+0], a1 = As[k][ty*4+1];
            float a2 = As[k][ty*4+2], a3 = As[k][ty*4+3];
            float b0 = Bs[k][tx*4+0], b1 = Bs[k][tx*4+1];
            float b2 = Bs[k][tx*4+2], b3 = Bs[k][tx*4+3];
            acc[0][0] += a0*b0; acc[0][1] += a0*b1; acc[0][2] += a0*b2; acc[0][3] += a0*b3;
            acc[1][0] += a1*b0; acc[1][1] += a1*b1; acc[1][2] += a1*b2; acc[1][3] += a1*b3;
            acc[2][0] += a2*b0; acc[2][1] += a2*b1; acc[2][2] += a2*b2; acc[2][3] += a2*b3;
            acc[3][0] += a3*b0; acc[3][1] += a3*b1; acc[3][2] += a3*b2; acc[3][3] += a3*b3;
        }
    }
    #pragma unroll
    for (int i = 0; i < 4; ++i) {
        int m = mBase + ty*4 + i;
        #pragma unroll
        for (int j = 0; j < 4; ++j) {
            int n = nBase + tx*4 + j;
            C[(size_t)m * G4 + n] = acc[i][j] + bih[n] + bhh[n];
        }
    }
}

// ---- LSTM recurrence over one time-chunk; one block per (dir, b) ----------
__global__ __launch_bounds__(512, 2) void lstm_chunk(
    const float* __restrict__ gxf,        // (TC*B, 512) chunk-local, fwd order
    const float* __restrict__ gxr,        // (TC*B, 512) chunk-local, bwd order
    const float* __restrict__ whhf,
    const float* __restrict__ whhr,
    float* __restrict__ h_state,          // (2, B, 128)
    float* __restrict__ c_state,          // (2, B, 128)
    float* __restrict__ out_all,          // x1 (T*B, 256) at col dir*128, or null
    int t_base, int TC)
{
    int blk = blockIdx.x;
    int dir = blk >> 7;
    int b   = blk & 127;
    const float* gx  = dir ? gxr : gxf;
    const float* whh = dir ? whhr : whhf;
    int tid = threadIdx.x;

    float w[128];
    #pragma unroll
    for (int k = 0; k < 128; k += 4) {
        float4 v = *reinterpret_cast<const float4*>(whh + (size_t)tid * 128 + k);
        w[k] = v.x; w[k+1] = v.y; w[k+2] = v.z; w[k+3] = v.w;
    }

    __shared__ float h_s[128];
    __shared__ float gates_s[512];
    int sbase = (dir * BB + b) * HH;
    float c = 0.f;
    if (tid < 128) {
        h_s[tid] = h_state[sbase + tid];
        c = c_state[sbase + tid];
    }
    __syncthreads();

    for (int s = 0; s < TC; ++s) {
        float gin = gx[((size_t)s * BB + b) * G4 + tid];
        float a0 = 0.f, a1 = 0.f, a2 = 0.f, a3 = 0.f;
        #pragma unroll
        for (int k = 0; k < 128; k += 4) {
            float4 hv = *reinterpret_cast<const float4*>(&h_s[k]);
            a0 += w[k+0] * hv.x;
            a1 += w[k+1] * hv.y;
            a2 += w[k+2] * hv.z;
            a3 += w[k+3] * hv.w;
        }
        float gate = gin + ((a0 + a1) + (a2 + a3));
        int grp = tid >> 7;           // 0:i 1:f 2:g 3:o — wave-uniform
        float act;
        if (grp == 2) act = tanhf(gate);
        else          act = 1.f / (1.f + __expf(-gate));
        gates_s[tid] = act;
        __syncthreads();
        if (tid < 128) {
            float ig = gates_s[tid];
            float fg = gates_s[128 + tid];
            float gg = gates_s[256 + tid];
            float og = gates_s[384 + tid];
            c = fg * c + ig * gg;
            float h = og * tanhf(c);
            h_s[tid] = h;
            if (out_all) {
                int t = dir ? (TT - 1 - (t_base + s)) : (t_base + s);
                out_all[((size_t)t * BB + b) * K1 + dir * HH + tid] = h;
            }
        }
        __syncthreads();
    }
    if (tid < 128) {
        h_state[sbase + tid] = h_s[tid];
        c_state[sbase + tid] = c;
    }
}

// ---- FC head --------------------------------------------------------------
__global__ void fc_kernel(const float* __restrict__ h_state,  // (2,B,128)
                          const float* __restrict__ fc_w,     // (3,256)
                          const float* __restrict__ fc_b,     // (3,)
                          float* __restrict__ out) {          // (B,3)
    int tid = blockIdx.x * blockDim.x + threadIdx.x;
    if (tid >= BB * 3) return;
    int b = tid / 3;
    int c = tid % 3;
    float acc = 0.f;
    for (int j = 0; j < 256; ++j) {
        float v = (j < HH) ? h_state[((size_t)0 * BB + b) * HH + j]
                           : h_state[((size_t)1 * BB + b) * HH + (j - HH)];
        acc += v * fc_w[c * 256 + j];
    }
    out[b * 3 + c] = acc + fc_b[c];
}

extern "C" void kernel_launch(void* const* d_in, const int* in_sizes, int n_in,
                              void* d_out, int out_size, void* d_ws, size_t ws_size,
                              hipStream_t stream) {
    const int*   x        = (const int*)  d_in[0];
    const float* emb      = (const float*)d_in[1];
    const float* w_ih_l0  = (const float*)d_in[2];
    const float* w_hh_l0  = (const float*)d_in[3];
    const float* b_ih_l0  = (const float*)d_in[4];
    const float* b_hh_l0  = (const float*)d_in[5];
    const float* w_ih_l0r = (const float*)d_in[6];
    const float* w_hh_l0r = (const float*)d_in[7];
    const float* b_ih_l0r = (const float*)d_in[8];
    const float* b_hh_l0r = (const float*)d_in[9];
    const float* w_ih_l1  = (const float*)d_in[10];
    const float* w_hh_l1  = (const float*)d_in[11];
    const float* b_ih_l1  = (const float*)d_in[12];
    const float* b_hh_l1  = (const float*)d_in[13];
    const float* w_ih_l1r = (const float*)d_in[14];
    const float* w_hh_l1r = (const float*)d_in[15];
    const float* b_ih_l1r = (const float*)d_in[16];
    const float* b_hh_l1r = (const float*)d_in[17];
    const float* fc_w     = (const float*)d_in[18];
    const float* fc_b     = (const float*)d_in[19];
    float* out = (float*)d_out;
    (void)in_sizes; (void)n_in; (void)out_size;

    // ---- workspace layout, adaptive time-chunk size ----
    size_t x1_b    = (size_t)TT * BB * K1 * 4;          // 67.1 MB
    size_t state_b = (size_t)2 * BB * HH * 4;           // 128 KB each (h, c)
    int TC = 512;
    while (TC > 8) {
        size_t chunk2 = (size_t)TC * BB * G4 * 4 * 2;
        if (x1_b + 2 * state_b + chunk2 + 4096 <= ws_size) break;
        TC >>= 1;
    }
    char* ws = (char*)d_ws;
    size_t off = 0;
    float* x1      = (float*)(ws + off); off += x1_b;
    float* gxf     = (float*)(ws + off); off += (size_t)TC * BB * G4 * 4;
    float* gxr     = (float*)(ws + off); off += (size_t)TC * BB * G4 * 4;
    float* h_state = (float*)(ws + off); off += state_b;
    float* c_state = (float*)(ws + off); off += state_b;

    int NC = TT / TC;
    dim3 ggrid(TC * BB / 64, G4 / 64);

    // ---- layer 0 ----
    hipMemsetAsync(h_state, 0, state_b, stream);
    hipMemsetAsync(c_state, 0, state_b, stream);
    for (int ci = 0; ci < NC; ++ci) {
        int t0 = ci * TC;
        gemm_l0<<<ggrid, 256, 0, stream>>>(x, emb, w_ih_l0,  b_ih_l0,  b_hh_l0,  gxf, t0, +1);
        gemm_l0<<<ggrid, 256, 0, stream>>>(x, emb, w_ih_l0r, b_ih_l0r, b_hh_l0r, gxr, TT - 1 - t0, -1);
        lstm_chunk<<<256, 512, 0, stream>>>(gxf, gxr, w_hh_l0, w_hh_l0r,
                                            h_state, c_state, x1, t0, TC);
    }
    // ---- layer 1 ----
    hipMemsetAsync(h_state, 0, state_b, stream);
    hipMemsetAsync(c_state, 0, state_b, stream);
    for (int ci = 0; ci < NC; ++ci) {
        int t0 = ci * TC;
        gemm_l1<<<ggrid, 256, 0, stream>>>(x1, w_ih_l1,  b_ih_l1,  b_hh_l1,  gxf, t0, +1);
        gemm_l1<<<ggrid, 256, 0, stream>>>(x1, w_ih_l1r, b_ih_l1r, b_hh_l1r, gxr, TT - 1 - t0, -1);
        lstm_chunk<<<256, 512, 0, stream>>>(gxf, gxr, w_hh_l1, w_hh_l1r,
                                            h_state, c_state, nullptr, t0, TC);
    }
    // ---- FC head ----
    fc_kernel<<<2, 192, 0, stream>>>(h_state, fc_w, fc_b, out);
}

// Round 3
// 1194.436 us; speedup vs baseline: 1.4458x; 1.4458x over previous
//
#include <hip/hip_runtime.h>
#include <hip/hip_bf16.h>
#include <math.h>

#define TT 512   // T
#define BB 128   // B
#define EE 100   // embed dim
#define HH 128   // hidden
#define G4 512   // 4*H
#define K1 256   // 2*H

typedef __attribute__((ext_vector_type(8))) short bf16x8;
typedef __attribute__((ext_vector_type(4))) float f32x4;

__device__ inline void split2(float v, unsigned short& hi, unsigned short& lo) {
    __hip_bfloat16 h = __float2bfloat16(v);
    float hf = __bfloat162float(h);
    __hip_bfloat16 l = __float2bfloat16(v - hf);
    hi = *reinterpret_cast<unsigned short*>(&h);
    lo = *reinterpret_cast<unsigned short*>(&l);
}

__device__ inline void gload16(const void* g, void* l) {
    __builtin_amdgcn_global_load_lds(
        (const __attribute__((address_space(1))) void*)g,
        (__attribute__((address_space(3))) void*)l, 16, 0, 0);
}

// ---- embedding -> xs2 bf16 [hi(128) | lo(128)] per (t,b) row ---------------
__global__ void embed_cvt(const int* __restrict__ x, const float* __restrict__ emb,
                          unsigned short* __restrict__ xs2) {
    int row = blockIdx.x;          // t*B + b
    int k = threadIdx.x;           // 0..127
    int b = row & 127, t = row >> 7;
    int tok = x[b * TT + t];
    float v = (k < EE) ? emb[(size_t)tok * EE + k] : 0.f;
    unsigned short hi, lo;
    split2(v, hi, lo);
    xs2[(size_t)row * 256 + k] = hi;
    xs2[(size_t)row * 256 + 128 + k] = lo;
}

// ---- weight -> bf16 [hi(Kp) | lo(Kp)] per row ------------------------------
__global__ void wcvt(const float* __restrict__ src, int Kin, int Kp,
                     unsigned short* __restrict__ dst) {
    int n = blockIdx.x;            // 0..511
    int k = threadIdx.x;           // 0..Kp-1
    float v = (k < Kin) ? src[(size_t)n * Kin + k] : 0.f;
    unsigned short hi, lo;
    split2(v, hi, lo);
    dst[(size_t)n * 2 * Kp + k] = hi;
    dst[(size_t)n * 2 * Kp + Kp + k] = lo;
}

// ---- MFMA GEMM: C[s*128+b][n] = sum_k A2[t(s)*128+b][k]*W2[n][k] + bias ----
// A2 rows bf16 (length K2), W2 (512 x K2) bf16. 128x128 tile, 4 waves, BK=64.
// LDS swizzle: byte ^= (row&7)<<4, applied via pre-permuted global source.
template<int K2>
__global__ __launch_bounds__(256) void gemm_mfma(
    const unsigned short* __restrict__ A2,
    const unsigned short* __restrict__ W2,
    const float* __restrict__ bih, const float* __restrict__ bhh,
    float* __restrict__ C, int t_base, int t_step)
{
    __shared__ bf16x8 As[1024];   // 128 rows x 128 B (64 bf16), swizzled
    __shared__ bf16x8 Bs[1024];
    int tid = threadIdx.x;
    int s = blockIdx.x;
    int t = t_base + t_step * s;
    int nBase = blockIdx.y * 128;
    const unsigned short* Abase = A2 + (size_t)t * BB * K2;
    const unsigned short* Wbase = W2 + (size_t)nBase * K2;
    int lane = tid & 63, wid = tid >> 6;
    int wr = wid >> 1, wc = wid & 1;
    int l15 = lane & 15, g = lane >> 4;

    f32x4 acc[4][4];
    const f32x4 z = {0.f, 0.f, 0.f, 0.f};
    #pragma unroll
    for (int i = 0; i < 4; ++i)
        #pragma unroll
        for (int j = 0; j < 4; ++j) acc[i][j] = z;

    for (int kt = 0; kt < K2 / 64; ++kt) {
        #pragma unroll
        for (int j = 0; j < 4; ++j) {
            int p = tid + j * 256;
            int row = p >> 3;
            int k16 = (p & 7) ^ (row & 7);   // pre-swizzled source chunk
            size_t goff = (size_t)row * K2 + kt * 64 + k16 * 8;
            gload16(Abase + goff, &As[p]);
            gload16(Wbase + goff, &Bs[p]);
        }
        __syncthreads();
        #pragma unroll
        for (int ks = 0; ks < 2; ++ks) {
            bf16x8 af[4], bfr[4];
            #pragma unroll
            for (int i = 0; i < 4; ++i) {
                int arow = wr * 64 + i * 16 + l15;
                int abyte = arow * 128 + ((ks * 64 + g * 16) ^ ((arow & 7) << 4));
                af[i] = As[abyte >> 4];
                int brow = wc * 64 + i * 16 + l15;
                int bbyte = brow * 128 + ((ks * 64 + g * 16) ^ ((brow & 7) << 4));
                bfr[i] = Bs[bbyte >> 4];
            }
            #pragma unroll
            for (int i = 0; i < 4; ++i)
                #pragma unroll
                for (int j = 0; j < 4; ++j)
                    acc[i][j] = __builtin_amdgcn_mfma_f32_16x16x32_bf16(
                        af[i], bfr[j], acc[i][j], 0, 0, 0);
        }
        __syncthreads();
    }
    // epilogue: D row = (lane>>4)*4 + r, col = lane&15 (verified mapping)
    #pragma unroll
    for (int i = 0; i < 4; ++i) {
        size_t crow0 = (size_t)s * 128 + wr * 64 + i * 16 + g * 4;
        #pragma unroll
        for (int j = 0; j < 4; ++j) {
            int col = nBase + wc * 64 + j * 16 + l15;
            float bsum = bih[col] + bhh[col];
            #pragma unroll
            for (int r = 0; r < 4; ++r)
                C[(crow0 + r) * G4 + col] = acc[i][j][r] + bsum;
        }
    }
}

// ---- LSTM recurrence over one time-chunk; one block per (dir, b) ----------
__global__ __launch_bounds__(512, 2) void lstm_chunk(
    const float* __restrict__ gxf,        // (TC*B, 512) chunk-local, fwd order
    const float* __restrict__ gxr,        // (TC*B, 512) chunk-local, bwd order
    const float* __restrict__ whhf,
    const float* __restrict__ whhr,
    float* __restrict__ h_state,          // (2, B, 128)
    float* __restrict__ c_state,          // (2, B, 128)
    unsigned short* __restrict__ out_x1,  // x1_2 (T*B, 512) bf16 [hi(256)|lo(256)], or null
    int t_base, int TC)
{
    int blk = blockIdx.x;
    int dir = blk >> 7;
    int b   = blk & 127;
    const float* gx  = dir ? gxr : gxf;
    const float* whh = dir ? whhr : whhf;
    int tid = threadIdx.x;

    float w[128];
    #pragma unroll
    for (int k = 0; k < 128; k += 4) {
        float4 v = *reinterpret_cast<const float4*>(whh + (size_t)tid * 128 + k);
        w[k] = v.x; w[k+1] = v.y; w[k+2] = v.z; w[k+3] = v.w;
    }

    __shared__ float h_s[128];
    __shared__ float gates_s[512];
    int sbase = (dir * BB + b) * HH;
    float c = 0.f;
    if (tid < 128) {
        h_s[tid] = h_state[sbase + tid];
        c = c_state[sbase + tid];
    }
    __syncthreads();

    for (int s = 0; s < TC; ++s) {
        float gin = gx[((size_t)s * BB + b) * G4 + tid];
        float a0 = 0.f, a1 = 0.f, a2 = 0.f, a3 = 0.f;
        #pragma unroll
        for (int k = 0; k < 128; k += 4) {
            float4 hv = *reinterpret_cast<const float4*>(&h_s[k]);
            a0 += w[k+0] * hv.x;
            a1 += w[k+1] * hv.y;
            a2 += w[k+2] * hv.z;
            a3 += w[k+3] * hv.w;
        }
        float gate = gin + ((a0 + a1) + (a2 + a3));
        int grp = tid >> 7;           // 0:i 1:f 2:g 3:o — wave-uniform
        float act;
        if (grp == 2) act = tanhf(gate);
        else          act = 1.f / (1.f + __expf(-gate));
        gates_s[tid] = act;
        __syncthreads();
        if (tid < 128) {
            float ig = gates_s[tid];
            float fg = gates_s[128 + tid];
            float gg = gates_s[256 + tid];
            float og = gates_s[384 + tid];
            c = fg * c + ig * gg;
            float h = og * tanhf(c);
            h_s[tid] = h;
            if (out_x1) {
                int t = dir ? (TT - 1 - (t_base + s)) : (t_base + s);
                size_t base = ((size_t)t * BB + b) * 512;
                unsigned short hi, lo;
                split2(h, hi, lo);
                out_x1[base + dir * HH + tid] = hi;
                out_x1[base + 256 + dir * HH + tid] = lo;
            }
        }
        __syncthreads();
    }
    if (tid < 128) {
        h_state[sbase + tid] = h_s[tid];
        c_state[sbase + tid] = c;
    }
}

// ---- FC head --------------------------------------------------------------
__global__ void fc_kernel(const float* __restrict__ h_state,  // (2,B,128)
                          const float* __restrict__ fc_w,     // (3,256)
                          const float* __restrict__ fc_b,     // (3,)
                          float* __restrict__ out) {          // (B,3)
    int tid = blockIdx.x * blockDim.x + threadIdx.x;
    if (tid >= BB * 3) return;
    int b = tid / 3;
    int c = tid % 3;
    float acc = 0.f;
    for (int j = 0; j < 256; ++j) {
        float v = (j < HH) ? h_state[((size_t)0 * BB + b) * HH + j]
                           : h_state[((size_t)1 * BB + b) * HH + (j - HH)];
        acc += v * fc_w[c * 256 + j];
    }
    out[b * 3 + c] = acc + fc_b[c];
}

extern "C" void kernel_launch(void* const* d_in, const int* in_sizes, int n_in,
                              void* d_out, int out_size, void* d_ws, size_t ws_size,
                              hipStream_t stream) {
    const int*   x        = (const int*)  d_in[0];
    const float* emb      = (const float*)d_in[1];
    const float* w_ih_l0  = (const float*)d_in[2];
    const float* w_hh_l0  = (const float*)d_in[3];
    const float* b_ih_l0  = (const float*)d_in[4];
    const float* b_hh_l0  = (const float*)d_in[5];
    const float* w_ih_l0r = (const float*)d_in[6];
    const float* w_hh_l0r = (const float*)d_in[7];
    const float* b_ih_l0r = (const float*)d_in[8];
    const float* b_hh_l0r = (const float*)d_in[9];
    const float* w_ih_l1  = (const float*)d_in[10];
    const float* w_hh_l1  = (const float*)d_in[11];
    const float* b_ih_l1  = (const float*)d_in[12];
    const float* b_hh_l1  = (const float*)d_in[13];
    const float* w_ih_l1r = (const float*)d_in[14];
    const float* w_hh_l1r = (const float*)d_in[15];
    const float* b_ih_l1r = (const float*)d_in[16];
    const float* b_hh_l1r = (const float*)d_in[17];
    const float* fc_w     = (const float*)d_in[18];
    const float* fc_b     = (const float*)d_in[19];
    float* out = (float*)d_out;
    (void)in_sizes; (void)n_in; (void)out_size;

    // ---- workspace layout ----
    size_t xs2_b   = (size_t)TT * BB * 256 * 2;         // 33.6 MB
    size_t x1_b    = (size_t)TT * BB * 512 * 2;         // 67.1 MB (bf16 hi|lo)
    size_t w2l0_b  = (size_t)512 * 256 * 2;             // 256 KB
    size_t w2l1_b  = (size_t)512 * 512 * 2;             // 512 KB
    size_t state_b = (size_t)2 * BB * HH * 4;           // 128 KB
    size_t fixed = xs2_b + x1_b + 2 * w2l0_b + 2 * w2l1_b + 2 * state_b + 4096;
    int TC = 512;
    while (TC > 8) {
        size_t chunk2 = (size_t)TC * BB * G4 * 4 * 2;
        if (fixed + chunk2 <= ws_size) break;
        TC >>= 1;
    }
    char* ws = (char*)d_ws;
    size_t off = 0;
    unsigned short* xs2   = (unsigned short*)(ws + off); off += xs2_b;
    unsigned short* x1_2  = (unsigned short*)(ws + off); off += x1_b;
    unsigned short* w2l0f = (unsigned short*)(ws + off); off += w2l0_b;
    unsigned short* w2l0r = (unsigned short*)(ws + off); off += w2l0_b;
    unsigned short* w2l1f = (unsigned short*)(ws + off); off += w2l1_b;
    unsigned short* w2l1r = (unsigned short*)(ws + off); off += w2l1_b;
    float* h_state = (float*)(ws + off); off += state_b;
    float* c_state = (float*)(ws + off); off += state_b;
    float* gxf     = (float*)(ws + off); off += (size_t)TC * BB * G4 * 4;
    float* gxr     = (float*)(ws + off);

    int NC = TT / TC;
    dim3 ggrid(TC, 4);

    // ---- precompute bf16 hi|lo forms ----
    embed_cvt<<<TT * BB, 128, 0, stream>>>(x, emb, xs2);
    wcvt<<<512, 128, 0, stream>>>(w_ih_l0,  EE, 128, w2l0f);
    wcvt<<<512, 128, 0, stream>>>(w_ih_l0r, EE, 128, w2l0r);
    wcvt<<<512, 256, 0, stream>>>(w_ih_l1,  K1, 256, w2l1f);
    wcvt<<<512, 256, 0, stream>>>(w_ih_l1r, K1, 256, w2l1r);

    // ---- layer 0 ----
    hipMemsetAsync(h_state, 0, state_b, stream);
    hipMemsetAsync(c_state, 0, state_b, stream);
    for (int ci = 0; ci < NC; ++ci) {
        int t0 = ci * TC;
        gemm_mfma<256><<<ggrid, 256, 0, stream>>>(xs2, w2l0f, b_ih_l0,  b_hh_l0,  gxf, t0, +1);
        gemm_mfma<256><<<ggrid, 256, 0, stream>>>(xs2, w2l0r, b_ih_l0r, b_hh_l0r, gxr, TT - 1 - t0, -1);
        lstm_chunk<<<256, 512, 0, stream>>>(gxf, gxr, w_hh_l0, w_hh_l0r,
                                            h_state, c_state, x1_2, t0, TC);
    }
    // ---- layer 1 ----
    hipMemsetAsync(h_state, 0, state_b, stream);
    hipMemsetAsync(c_state, 0, state_b, stream);
    for (int ci = 0; ci < NC; ++ci) {
        int t0 = ci * TC;
        gemm_mfma<512><<<ggrid, 256, 0, stream>>>(x1_2, w2l1f, b_ih_l1,  b_hh_l1,  gxf, t0, +1);
        gemm_mfma<512><<<ggrid, 256, 0, stream>>>(x1_2, w2l1r, b_ih_l1r, b_hh_l1r, gxr, TT - 1 - t0, -1);
        lstm_chunk<<<256, 512, 0, stream>>>(gxf, gxr, w_hh_l1, w_hh_l1r,
                                            h_state, c_state, nullptr, t0, TC);
    }
    // ---- FC head ----
    fc_kernel<<<2, 192, 0, stream>>>(h_state, fc_w, fc_b, out);
}

// Round 4
// 1049.696 us; speedup vs baseline: 1.6452x; 1.1379x over previous
//
#include <hip/hip_runtime.h>
#include <hip/hip_bf16.h>
#include <math.h>

#define TT 512   // T
#define BB 128   // B
#define EE 100   // embed dim
#define HH 128   // hidden
#define G4 512   // 4*H
#define K1 256   // 2*H

typedef __attribute__((ext_vector_type(8))) short bf16x8;
typedef __attribute__((ext_vector_type(4))) float f32x4;
typedef __attribute__((ext_vector_type(2))) float f32x2;

__device__ inline void split2(float v, unsigned short& hi, unsigned short& lo) {
    __hip_bfloat16 h = __float2bfloat16(v);
    float hf = __bfloat162float(h);
    __hip_bfloat16 l = __float2bfloat16(v - hf);
    hi = *reinterpret_cast<unsigned short*>(&h);
    lo = *reinterpret_cast<unsigned short*>(&l);
}

__device__ inline void gload16(const void* g, void* l) {
    __builtin_amdgcn_global_load_lds(
        (const __attribute__((address_space(1))) void*)g,
        (__attribute__((address_space(3))) void*)l, 16, 0, 0);
}

// ---- embedding -> xs2 bf16 [hi(128) | lo(128)] per (t,b) row ---------------
__global__ void embed_cvt(const int* __restrict__ x, const float* __restrict__ emb,
                          unsigned short* __restrict__ xs2) {
    int row = blockIdx.x;          // t*B + b
    int k = threadIdx.x;           // 0..127
    int b = row & 127, t = row >> 7;
    int tok = x[b * TT + t];
    float v = (k < EE) ? emb[(size_t)tok * EE + k] : 0.f;
    unsigned short hi, lo;
    split2(v, hi, lo);
    xs2[(size_t)row * 256 + k] = hi;
    xs2[(size_t)row * 256 + 128 + k] = lo;
}

// ---- weight -> bf16 [hi(Kp) | lo(Kp)] per row ------------------------------
__global__ void wcvt(const float* __restrict__ src, int Kin, int Kp,
                     unsigned short* __restrict__ dst) {
    int n = blockIdx.x;            // 0..511
    int k = threadIdx.x;           // 0..Kp-1
    float v = (k < Kin) ? src[(size_t)n * Kin + k] : 0.f;
    unsigned short hi, lo;
    split2(v, hi, lo);
    dst[(size_t)n * 2 * Kp + k] = hi;
    dst[(size_t)n * 2 * Kp + Kp + k] = lo;
}

// ---- MFMA GEMM: C[s*128+b][n] = sum_k A2[t(s)*128+b][k]*W2[n][k] + bias ----
// grid = (4 n-tiles, TC s-tiles): n fastest so A-tile is L2-shared.
template<int K2>
__global__ __launch_bounds__(256) void gemm_mfma(
    const unsigned short* __restrict__ A2,
    const unsigned short* __restrict__ W2,
    const float* __restrict__ bih, const float* __restrict__ bhh,
    float* __restrict__ C, int t_base, int t_step)
{
    __shared__ bf16x8 As[1024];   // 128 rows x 128 B (64 bf16), swizzled
    __shared__ bf16x8 Bs[1024];
    int tid = threadIdx.x;
    int s = blockIdx.y;
    int t = t_base + t_step * s;
    int nBase = blockIdx.x * 128;
    const unsigned short* Abase = A2 + (size_t)t * BB * K2;
    const unsigned short* Wbase = W2 + (size_t)nBase * K2;
    int lane = tid & 63, wid = tid >> 6;
    int wr = wid >> 1, wc = wid & 1;
    int l15 = lane & 15, g = lane >> 4;

    f32x4 acc[4][4];
    const f32x4 z = {0.f, 0.f, 0.f, 0.f};
    #pragma unroll
    for (int i = 0; i < 4; ++i)
        #pragma unroll
        for (int j = 0; j < 4; ++j) acc[i][j] = z;

    for (int kt = 0; kt < K2 / 64; ++kt) {
        #pragma unroll
        for (int j = 0; j < 4; ++j) {
            int p = tid + j * 256;
            int row = p >> 3;
            int k16 = (p & 7) ^ (row & 7);   // pre-swizzled source chunk
            size_t goff = (size_t)row * K2 + kt * 64 + k16 * 8;
            gload16(Abase + goff, &As[p]);
            gload16(Wbase + goff, &Bs[p]);
        }
        __syncthreads();
        #pragma unroll
        for (int ks = 0; ks < 2; ++ks) {
            bf16x8 af[4], bfr[4];
            #pragma unroll
            for (int i = 0; i < 4; ++i) {
                int arow = wr * 64 + i * 16 + l15;
                int abyte = arow * 128 + ((ks * 64 + g * 16) ^ ((arow & 7) << 4));
                af[i] = As[abyte >> 4];
                int brow = wc * 64 + i * 16 + l15;
                int bbyte = brow * 128 + ((ks * 64 + g * 16) ^ ((brow & 7) << 4));
                bfr[i] = Bs[bbyte >> 4];
            }
            #pragma unroll
            for (int i = 0; i < 4; ++i)
                #pragma unroll
                for (int j = 0; j < 4; ++j)
                    acc[i][j] = __builtin_amdgcn_mfma_f32_16x16x32_bf16(
                        af[i], bfr[j], acc[i][j], 0, 0, 0);
        }
        __syncthreads();
    }
    #pragma unroll
    for (int i = 0; i < 4; ++i) {
        size_t crow0 = (size_t)s * 128 + wr * 64 + i * 16 + g * 4;
        #pragma unroll
        for (int j = 0; j < 4; ++j) {
            int col = nBase + wc * 64 + j * 16 + l15;
            float bsum = bih[col] + bhh[col];
            #pragma unroll
            for (int r = 0; r < 4; ++r)
                C[(crow0 + r) * G4 + col] = acc[i][j][r] + bsum;
        }
    }
}

__device__ inline float sig_fast(float z) {
    return __builtin_amdgcn_rcpf(1.f + __expf(-z));
}

// ---- LSTM recurrence: one block per (dir, b); 512 thr; quad-per-unit ------
// thread (u = tid>>2, q = tid&3): K-slice [32q,32q+32) of all 4 gate rows of
// unit u. Quad butterfly combines partials; one raw barrier per step;
// gin prefetched one step ahead (stays in flight across raw barrier).
__global__ __launch_bounds__(512, 2) void lstm_chunk(
    const float* __restrict__ gxf,        // (TC*B, 512) chunk-local, fwd order
    const float* __restrict__ gxr,        // (TC*B, 512) chunk-local, bwd order
    const float* __restrict__ whhf,
    const float* __restrict__ whhr,
    float* __restrict__ h_state,          // (2, B, 128)
    float* __restrict__ c_state,          // (2, B, 128)
    unsigned short* __restrict__ out_x1,  // x1_2 (T*B,512) bf16 [hi|lo], or null
    int t_base, int TC)
{
    int blk = blockIdx.x;
    int dir = blk >> 7;
    int b   = blk & 127;
    const float* gx  = dir ? gxr : gxf;
    const float* whh = dir ? whhr : whhf;
    int tid = threadIdx.x;
    int u = tid >> 2, q = tid & 3;

    // pack w rows {g*128+u}, K-slice [32q,32q+32) as f32x2 pairs (g0,g1),(g2,g3)
    f32x2 wp01[32], wp23[32];
    {
        const float* w0 = whh + ((size_t)(0 * 128 + u)) * 128 + q * 32;
        const float* w1 = whh + ((size_t)(1 * 128 + u)) * 128 + q * 32;
        const float* w2 = whh + ((size_t)(2 * 128 + u)) * 128 + q * 32;
        const float* w3 = whh + ((size_t)(3 * 128 + u)) * 128 + q * 32;
        #pragma unroll
        for (int kb = 0; kb < 8; ++kb) {
            float4 a = *reinterpret_cast<const float4*>(w0 + kb * 4);
            float4 bv = *reinterpret_cast<const float4*>(w1 + kb * 4);
            float4 cv = *reinterpret_cast<const float4*>(w2 + kb * 4);
            float4 dv = *reinterpret_cast<const float4*>(w3 + kb * 4);
            wp01[kb*4+0] = f32x2{a.x, bv.x}; wp23[kb*4+0] = f32x2{cv.x, dv.x};
            wp01[kb*4+1] = f32x2{a.y, bv.y}; wp23[kb*4+1] = f32x2{cv.y, dv.y};
            wp01[kb*4+2] = f32x2{a.z, bv.z}; wp23[kb*4+2] = f32x2{cv.z, dv.z};
            wp01[kb*4+3] = f32x2{a.w, bv.w}; wp23[kb*4+3] = f32x2{cv.w, dv.w};
        }
    }

    // ping-pong h buffer: quarter q at float offset 40q (bank-shifted, 16B-aligned)
    __shared__ float hb[2][160];
    int sbase = (dir * BB + b) * HH;
    int hslot = (u >> 5) * 40 + (u & 31);
    float c = c_state[sbase + u];
    float h = 0.f;
    if (q == 0) hb[0][hslot] = h_state[sbase + u];
    __syncthreads();

    float gin = gx[((size_t)0 * BB + b) * G4 + (q << 7) + u];

    for (int s = 0; s < TC; ++s) {
        int p = s & 1;
        float gin_next = 0.f;
        if (s + 1 < TC)
            gin_next = gx[((size_t)(s + 1) * BB + b) * G4 + (q << 7) + u];

        // dot over this thread's K-slice
        f32x2 acc01 = {0.f, 0.f}, acc23 = {0.f, 0.f};
        const float4* hb4 = reinterpret_cast<const float4*>(&hb[p][40 * q]);
        #pragma unroll
        for (int kb = 0; kb < 8; ++kb) {
            float4 hv = hb4[kb];
            float hvv[4] = {hv.x, hv.y, hv.z, hv.w};
            #pragma unroll
            for (int e = 0; e < 4; ++e) {
                f32x2 hh = {hvv[e], hvv[e]};
                acc01 = __builtin_elementwise_fma(wp01[kb*4+e], hh, acc01);
                acc23 = __builtin_elementwise_fma(wp23[kb*4+e], hh, acc23);
            }
        }
        // quad butterfly: all 4 lanes get full sums for gates 0..3
        f32x2 t;
        t.x = __shfl_xor(acc01.x, 1); t.y = __shfl_xor(acc01.y, 1); acc01 += t;
        t.x = __shfl_xor(acc23.x, 1); t.y = __shfl_xor(acc23.y, 1); acc23 += t;
        t.x = __shfl_xor(acc01.x, 2); t.y = __shfl_xor(acc01.y, 2); acc01 += t;
        t.x = __shfl_xor(acc23.x, 2); t.y = __shfl_xor(acc23.y, 2); acc23 += t;

        bool q0 = (q == 0), q1 = (q == 1), q2 = (q == 2);
        float pre = (q0 ? acc01.x : q1 ? acc01.y : q2 ? acc23.x : acc23.y) + gin;
        // unified activation: gate q==2 -> tanh = 2*sigma(2x)-1, else sigma(x)
        float fq = q2 ? 2.f : 1.f;
        float bq = q2 ? -1.f : 0.f;
        float y = sig_fast(pre * fq);
        float act = __builtin_fmaf(y, fq, bq);
        // share acts across the quad
        float v1 = __shfl_xor(act, 1);
        float v2 = __shfl_xor(act, 2);
        float v3 = __shfl_xor(act, 3);
        float ig = q0 ? act : q1 ? v1 : q2 ? v2 : v3;
        float fg = q0 ? v1  : q1 ? act: q2 ? v3 : v2;
        float gg = q0 ? v2  : q1 ? v3 : q2 ? act: v1;
        float og = q0 ? v3  : q1 ? v2 : q2 ? v1 : act;

        c = fg * c + ig * gg;
        float th = __builtin_fmaf(2.f, sig_fast(2.f * c), -1.f);
        h = og * th;

        if (q == 0) hb[p ^ 1][hslot] = h;
        if (out_x1 && q < 2) {
            int tg = dir ? (TT - 1 - (t_base + s)) : (t_base + s);
            size_t base = ((size_t)tg * BB + b) * 512;
            unsigned short hi, lo;
            split2(h, hi, lo);
            if (q == 0) out_x1[base + dir * HH + u] = hi;
            else        out_x1[base + 256 + dir * HH + u] = lo;
        }
        asm volatile("s_waitcnt lgkmcnt(0)" ::: "memory");
        __builtin_amdgcn_s_barrier();
        asm volatile("" ::: "memory");
        gin = gin_next;
    }
    if (q == 0) {
        h_state[sbase + u] = h;
        c_state[sbase + u] = c;
    }
}

// ---- FC head --------------------------------------------------------------
__global__ void fc_kernel(const float* __restrict__ h_state,  // (2,B,128)
                          const float* __restrict__ fc_w,     // (3,256)
                          const float* __restrict__ fc_b,     // (3,)
                          float* __restrict__ out) {          // (B,3)
    int tid = blockIdx.x * blockDim.x + threadIdx.x;
    if (tid >= BB * 3) return;
    int b = tid / 3;
    int c = tid % 3;
    float acc = 0.f;
    for (int j = 0; j < 256; ++j) {
        float v = (j < HH) ? h_state[((size_t)0 * BB + b) * HH + j]
                           : h_state[((size_t)1 * BB + b) * HH + (j - HH)];
        acc += v * fc_w[c * 256 + j];
    }
    out[b * 3 + c] = acc + fc_b[c];
}

extern "C" void kernel_launch(void* const* d_in, const int* in_sizes, int n_in,
                              void* d_out, int out_size, void* d_ws, size_t ws_size,
                              hipStream_t stream) {
    const int*   x        = (const int*)  d_in[0];
    const float* emb      = (const float*)d_in[1];
    const float* w_ih_l0  = (const float*)d_in[2];
    const float* w_hh_l0  = (const float*)d_in[3];
    const float* b_ih_l0  = (const float*)d_in[4];
    const float* b_hh_l0  = (const float*)d_in[5];
    const float* w_ih_l0r = (const float*)d_in[6];
    const float* w_hh_l0r = (const float*)d_in[7];
    const float* b_ih_l0r = (const float*)d_in[8];
    const float* b_hh_l0r = (const float*)d_in[9];
    const float* w_ih_l1  = (const float*)d_in[10];
    const float* w_hh_l1  = (const float*)d_in[11];
    const float* b_ih_l1  = (const float*)d_in[12];
    const float* b_hh_l1  = (const float*)d_in[13];
    const float* w_ih_l1r = (const float*)d_in[14];
    const float* w_hh_l1r = (const float*)d_in[15];
    const float* b_ih_l1r = (const float*)d_in[16];
    const float* b_hh_l1r = (const float*)d_in[17];
    const float* fc_w     = (const float*)d_in[18];
    const float* fc_b     = (const float*)d_in[19];
    float* out = (float*)d_out;
    (void)in_sizes; (void)n_in; (void)out_size;

    // ---- workspace layout ----
    size_t xs2_b   = (size_t)TT * BB * 256 * 2;         // 33.6 MB
    size_t x1_b    = (size_t)TT * BB * 512 * 2;         // 67.1 MB (bf16 hi|lo)
    size_t w2l0_b  = (size_t)512 * 256 * 2;             // 256 KB
    size_t w2l1_b  = (size_t)512 * 512 * 2;             // 512 KB
    size_t state_b = (size_t)2 * BB * HH * 4;           // 128 KB
    size_t fixed = xs2_b + x1_b + 2 * w2l0_b + 2 * w2l1_b + 2 * state_b + 4096;
    int TC = 512;
    while (TC > 8) {
        size_t chunk2 = (size_t)TC * BB * G4 * 4 * 2;
        if (fixed + chunk2 <= ws_size) break;
        TC >>= 1;
    }
    char* ws = (char*)d_ws;
    size_t off = 0;
    unsigned short* xs2   = (unsigned short*)(ws + off); off += xs2_b;
    unsigned short* x1_2  = (unsigned short*)(ws + off); off += x1_b;
    unsigned short* w2l0f = (unsigned short*)(ws + off); off += w2l0_b;
    unsigned short* w2l0r = (unsigned short*)(ws + off); off += w2l0_b;
    unsigned short* w2l1f = (unsigned short*)(ws + off); off += w2l1_b;
    unsigned short* w2l1r = (unsigned short*)(ws + off); off += w2l1_b;
    float* h_state = (float*)(ws + off); off += state_b;
    float* c_state = (float*)(ws + off); off += state_b;
    float* gxf     = (float*)(ws + off); off += (size_t)TC * BB * G4 * 4;
    float* gxr     = (float*)(ws + off);

    int NC = TT / TC;
    dim3 ggrid(4, TC);

    // ---- precompute bf16 hi|lo forms ----
    embed_cvt<<<TT * BB, 128, 0, stream>>>(x, emb, xs2);
    wcvt<<<512, 128, 0, stream>>>(w_ih_l0,  EE, 128, w2l0f);
    wcvt<<<512, 128, 0, stream>>>(w_ih_l0r, EE, 128, w2l0r);
    wcvt<<<512, 256, 0, stream>>>(w_ih_l1,  K1, 256, w2l1f);
    wcvt<<<512, 256, 0, stream>>>(w_ih_l1r, K1, 256, w2l1r);

    // ---- layer 0 ----
    hipMemsetAsync(h_state, 0, state_b, stream);
    hipMemsetAsync(c_state, 0, state_b, stream);
    for (int ci = 0; ci < NC; ++ci) {
        int t0 = ci * TC;
        gemm_mfma<256><<<ggrid, 256, 0, stream>>>(xs2, w2l0f, b_ih_l0,  b_hh_l0,  gxf, t0, +1);
        gemm_mfma<256><<<ggrid, 256, 0, stream>>>(xs2, w2l0r, b_ih_l0r, b_hh_l0r, gxr, TT - 1 - t0, -1);
        lstm_chunk<<<256, 512, 0, stream>>>(gxf, gxr, w_hh_l0, w_hh_l0r,
                                            h_state, c_state, x1_2, t0, TC);
    }
    // ---- layer 1 ----
    hipMemsetAsync(h_state, 0, state_b, stream);
    hipMemsetAsync(c_state, 0, state_b, stream);
    for (int ci = 0; ci < NC; ++ci) {
        int t0 = ci * TC;
        gemm_mfma<512><<<ggrid, 256, 0, stream>>>(x1_2, w2l1f, b_ih_l1,  b_hh_l1,  gxf, t0, +1);
        gemm_mfma<512><<<ggrid, 256, 0, stream>>>(x1_2, w2l1r, b_ih_l1r, b_hh_l1r, gxr, TT - 1 - t0, -1);
        lstm_chunk<<<256, 512, 0, stream>>>(gxf, gxr, w_hh_l1, w_hh_l1r,
                                            h_state, c_state, nullptr, t0, TC);
    }
    // ---- FC head ----
    fc_kernel<<<2, 192, 0, stream>>>(h_state, fc_w, fc_b, out);
}